// Round 3
// baseline (96554.523 us; speedup 1.0000x reference)
//
#include <hip/hip_runtime.h>
#include <hip/hip_fp16.h>
#include <hip/hip_cooperative_groups.h>

namespace cg = cooperative_groups;

// B=32, T=512, E=512, TDEC=400, NMEL=80, RNN=1024, PRE=256, ADIM=128, KS=31
// outputs: mel [32][80][400] | gate [32][400] | align [32][400][512]
#define GATE_OFF  1024000
#define ALIGN_OFF 1036800

typedef _Float16 f16x8 __attribute__((ext_vector_type(8)));
typedef _Float16 f16x4 __attribute__((ext_vector_type(4)));
typedef float f32x4 __attribute__((ext_vector_type(4)));
#define MFMA161632(a,b,c) __builtin_amdgcn_mfma_f32_16x16x32_f16(a,b,c,0,0,0)

struct Ptrs {
  const float *mem, *dec, *Wpre1, *Wpre2, *WihA, *WhhA, *bihA, *bhhA,
              *WihD, *WhhD, *bihD, *bhhD, *Wq, *Wm, *Wsc, *bsc,
              *Wlc, *Wld, *Wproj, *bproj, *Wgate, *bgate;
  float *out;
  float *Mc, *W1T, *W2T, *WmT, *p1, *gpA, *gpD;
  __half *pmH, *locH, *WqTh, *memH, *WAm, *WDm, *preH, *preL;
  float *acp, *acn, *dh, *dc, *ctxP, *ctxN, *aw, *awc;
  __half *ahpH, *ahpL, *ahnH, *ahnL, *ctxPH, *ctxPL, *ctxNH, *ctxNL, *dhH, *dhL;
  // double-buffer bases for persistent loop
  float *AC2[2], *CT2[2];
  __half *AHH2[2], *AHL2[2], *CTH2[2], *CTL2[2];
};

__device__ __forceinline__ float rcpf(float x){ return __builtin_amdgcn_rcpf(x); }
__device__ __forceinline__ float sigf(float x){
  x = fminf(fmaxf(x,-30.f),30.f);
  return rcpf(1.f+__expf(-x));
}
__device__ __forceinline__ float tanhfast(float x){
  x = fminf(fmaxf(x,-15.f),15.f);
  float e = __expf(2.f*x);
  return (e-1.f)*rcpf(e+1.f);
}

__global__ void k_init(float* p, int n){
  int i = blockIdx.x*256 + threadIdx.x;
  if (i < n) p[i] = 0.f;
}

__global__ __launch_bounds__(1024) void k_memh(Ptrs P){
  int i = blockIdx.x*1024 + threadIdx.x;
  if (i < 8388608) P.memH[i] = __float2half(P.mem[i]);
}

__global__ void k_xform(Ptrs P){
  int i = blockIdx.x*256 + threadIdx.x;
  if (i < 20480){ int k=i>>8, p=i&255; P.W1T[i] = P.Wpre1[p*80 + k]; return; }
  i -= 20480;
  if (i < 65536){ int k=i>>8, p=i&255; P.W2T[i] = P.Wpre2[p*256 + k]; return; }
  i -= 65536;
  if (i < 131072){ P.WqTh[i] = __float2half(P.Wq[i]); return; }  // a-major copy [128][1024]
  i -= 131072;
  if (i < 65536){ int e=i>>7, a=i&127; P.WmT[i] = P.Wm[a*512 + e]; return; }
  i -= 65536;
  if (i < 7936){
    int c = i/3968, r = i%3968, k = r>>7, a = r&127;
    float s = 0.f;
    for (int f=0; f<31; f++) s += P.Wld[a*31+f]*P.Wlc[f*62 + c*31 + k];
    P.Mc[i] = s;
  }
}

// att weights -> MFMA B-fragment layout, fp16.
__global__ __launch_bounds__(256) void k_tA(Ptrs P){
  int idx = blockIdx.x*256 + threadIdx.x;          // [0, 917504)
  int lane = idx&63, jt16 = (idx>>6)&255, ks = idx>>14;   // ks<56
  int kb = ks*32 + ((lane>>4)<<3);
  int j = (jt16<<4) + (lane&15);
  const float* src;
  if (kb < 768) src = P.WihA + (size_t)j*768 + kb;
  else          src = P.WhhA + (size_t)j*1024 + (kb-768);
  float4 v0 = *(const float4*)(src);
  float4 v1 = *(const float4*)(src+4);
  union { int4 i4; __half h[8]; } u;
  u.h[0]=__float2half(v0.x); u.h[1]=__float2half(v0.y);
  u.h[2]=__float2half(v0.z); u.h[3]=__float2half(v0.w);
  u.h[4]=__float2half(v1.x); u.h[5]=__float2half(v1.y);
  u.h[6]=__float2half(v1.z); u.h[7]=__float2half(v1.w);
  *(int4*)(P.WAm + (size_t)idx*8) = u.i4;
}
__global__ __launch_bounds__(256) void k_tD(Ptrs P){
  int idx = blockIdx.x*256 + threadIdx.x;          // [0, 1310720)
  int lane = idx&63, jt16 = (idx>>6)&255, ks = idx>>14;   // ks<80
  int kb = ks*32 + ((lane>>4)<<3);
  int j = (jt16<<4) + (lane&15);
  const float* src;
  if (kb < 1536) src = P.WihD + (size_t)j*1536 + kb;
  else           src = P.WhhD + (size_t)j*1024 + (kb-1536);
  float4 v0 = *(const float4*)(src);
  float4 v1 = *(const float4*)(src+4);
  union { int4 i4; __half h[8]; } u;
  u.h[0]=__float2half(v0.x); u.h[1]=__float2half(v0.y);
  u.h[2]=__float2half(v0.z); u.h[3]=__float2half(v0.w);
  u.h[4]=__float2half(v1.x); u.h[5]=__float2half(v1.y);
  u.h[6]=__float2half(v1.z); u.h[7]=__float2half(v1.w);
  *(int4*)(P.WDm + (size_t)idx*8) = u.i4;
}

__global__ __launch_bounds__(256) void k_pn1(Ptrs P){
  __shared__ __align__(16) float pinL[8*80];
  int bid = blockIdx.x, tid = threadIdx.x;
  int r0 = bid*8;
  for (int i=tid; i<640; i+=256){
    int bi = i/80, m = i%80;
    int row = r0+bi, tt = row>>5, b = row&31;
    pinL[bi*80+m] = (tt==0) ? 0.f : P.dec[(size_t)b*32000 + m*400 + (tt-1)];
  }
  __syncthreads();
  int p = tid;
  float acc[8];
  #pragma unroll
  for (int bi=0;bi<8;bi++) acc[bi]=0.f;
  #pragma unroll
  for (int kq=0; kq<20; kq++){
    int k0 = kq*4;
    float w0 = P.W1T[(k0+0)*256+p], w1 = P.W1T[(k0+1)*256+p];
    float w2 = P.W1T[(k0+2)*256+p], w3 = P.W1T[(k0+3)*256+p];
    #pragma unroll
    for (int bi=0;bi<8;bi++){
      float4 x = *(float4*)(pinL + bi*80 + k0);
      acc[bi] += x.x*w0 + x.y*w1 + x.z*w2 + x.w*w3;
    }
  }
  #pragma unroll
  for (int bi=0;bi<8;bi++) P.p1[(size_t)(r0+bi)*256 + p] = fmaxf(acc[bi],0.f);
}

__global__ __launch_bounds__(256) void k_pn2(Ptrs P){
  __shared__ __align__(16) float xL[8*256];
  int bid = blockIdx.x, tid = threadIdx.x;
  size_t r0 = (size_t)bid*8;
  for (int i4=tid; i4<512; i4+=256)
    *(float4*)(xL + i4*4) = *(const float4*)(P.p1 + r0*256 + i4*4);
  __syncthreads();
  int p = tid;
  float acc[8];
  #pragma unroll
  for (int bi=0;bi<8;bi++) acc[bi]=0.f;
  for (int kq=0; kq<64; kq++){
    int k0 = kq*4;
    float w0 = P.W2T[(k0+0)*256+p], w1 = P.W2T[(k0+1)*256+p];
    float w2 = P.W2T[(k0+2)*256+p], w3 = P.W2T[(k0+3)*256+p];
    #pragma unroll
    for (int bi=0;bi<8;bi++){
      float4 x = *(float4*)(xL + bi*256 + k0);
      acc[bi] += x.x*w0 + x.y*w1 + x.z*w2 + x.w*w3;
    }
  }
  #pragma unroll
  for (int bi=0;bi<8;bi++){
    float v = fmaxf(acc[bi],0.f);
    __half h = __float2half(v);
    size_t off = (r0+bi)*256 + p;
    P.preH[off] = h;
    P.preL[off] = __float2half(v - __half2float(h));
  }
}

__global__ __launch_bounds__(256) void k_pm(Ptrs P){
  __shared__ __align__(16) float memL[8*512];
  int bid = blockIdx.x, tid = threadIdx.x;
  size_t r0 = (size_t)bid*8;
  for (int i4=tid; i4<1024; i4+=256)
    *(float4*)(memL + i4*4) = *(const float4*)(P.mem + r0*512 + i4*4);
  __syncthreads();
  int a = tid&127, rq = tid>>7;
  float acc[4];
  #pragma unroll
  for (int ri=0;ri<4;ri++) acc[ri]=0.f;
  for (int kq=0; kq<128; kq++){
    int k0 = kq*4;
    float w0 = P.WmT[(k0+0)*128+a], w1 = P.WmT[(k0+1)*128+a];
    float w2 = P.WmT[(k0+2)*128+a], w3 = P.WmT[(k0+3)*128+a];
    #pragma unroll
    for (int ri=0;ri<4;ri++){
      float4 x = *(float4*)(memL + (rq*4+ri)*512 + k0);
      acc[ri] += x.x*w0 + x.y*w1 + x.z*w2 + x.w*w3;
    }
  }
  #pragma unroll
  for (int ri=0;ri<4;ri++) P.pmH[(r0 + rq*4+ri)*128 + a] = __float2half(acc[ri]);
}

// ================= persistent cooperative kernel: full 400-step loop =================
// phase1 units: [0,256) attGEMM(t) | [256,512) decGEMM(t-1) | [512,556) proj(t-2) | [556,812) conv(t)
// phase2:       wg<64 att-act+q+scores+softmax+ctx(t) | wg in [64,96) dec-act(t-1)
__global__ __launch_bounds__(512, 4) void k_loop(Ptrs P){
  cg::grid_group grid = cg::this_grid();
  __shared__ __align__(16) char smraw[40960];
  __half* xfh = (__half*)smraw;      // [10240]
  __half* xfl = xfh + 10240;         // [10240]
  float*  smf = (float*)smraw;
  int wg = blockIdx.x, NW = gridDim.x, tid = threadIdx.x;
  int wid = tid>>6, lane = tid&63;

  for (int t = 0; t <= 401; ++t){
    int t1 = t&1;
    float* acp  = t1 ? P.AC2[1] : P.AC2[0];
    float* acn  = t1 ? P.AC2[0] : P.AC2[1];
    float* ctxN = t1 ? P.CT2[0] : P.CT2[1];
    const __half* ahpH  = t1 ? P.AHH2[1] : P.AHH2[0];
    const __half* ahpL  = t1 ? P.AHL2[1] : P.AHL2[0];
    __half*       ahnH  = t1 ? P.AHH2[0] : P.AHH2[1];
    __half*       ahnL  = t1 ? P.AHL2[0] : P.AHL2[1];
    const __half* ctxPH = t1 ? P.CTH2[1] : P.CTH2[0];
    const __half* ctxPL = t1 ? P.CTL2[1] : P.CTL2[0];
    __half*       ctxNH = t1 ? P.CTH2[0] : P.CTH2[1];
    __half*       ctxNL = t1 ? P.CTL2[0] : P.CTL2[1];

    // ---------------- PHASE 1 ----------------
    for (int u = wg; u < 812; u += NW){
      if (u < 256){
        if (t < 400){
          // attGEMM(t): x = [pre_t(256) | ctxP(512) | ahp(1024)], hi/lo fp16
          int jt = u>>3, c = u&7;
          for (int i = tid; i < 1792; i += 512){
            int p = i & 1, q = i >> 1;
            int b = q / 28, k8 = q - b*28;
            int kg = c*224 + k8*8;
            const __half* s;
            if (kg < 256)      s = (p ? P.preL : P.preH) + (size_t)(t*32+b)*256 + kg;
            else if (kg < 768) s = (p ? ctxPL : ctxPH) + b*512 + (kg-256);
            else               s = (p ? ahpL : ahpH) + b*1024 + (kg-768);
            int m = b>>4, ln = ((k8&3)<<4)|(b&15), ksl = k8>>2;
            __half* xfp = p ? xfl : xfh;
            *(int4*)(xfp + (((ksl<<1)|m)<<9) + ln*8) = *(const int4*)s;
          }
          __syncthreads();
          int jt16 = jt*8 + wid;
          f32x4 acc0 = {0.f,0.f,0.f,0.f}, acc1 = {0.f,0.f,0.f,0.f};
          for (int ksl=0; ksl<7; ksl++){
            int ks = c*7 + ksl;
            f16x8 bw = *(const f16x8*)(P.WAm + (size_t)ks*131072 + (size_t)jt16*512 + lane*8);
            f16x8 a0h = *(const f16x8*)(xfh + (ksl<<10) + lane*8);
            f16x8 a1h = *(const f16x8*)(xfh + (ksl<<10) + 512 + lane*8);
            f16x8 a0l = *(const f16x8*)(xfl + (ksl<<10) + lane*8);
            f16x8 a1l = *(const f16x8*)(xfl + (ksl<<10) + 512 + lane*8);
            acc0 = MFMA161632(a0h, bw, acc0);
            acc1 = MFMA161632(a1h, bw, acc1);
            acc0 = MFMA161632(a0l, bw, acc0);
            acc1 = MFMA161632(a1l, bw, acc1);
          }
          int colj = (jt16<<4) + (lane&15);
          int rb = (lane>>4)<<2;
          float* gA = P.gpA + (size_t)c*131072 + colj;
          #pragma unroll
          for (int r=0;r<4;r++){
            gA[(size_t)(rb + r)*4096]      = acc0[r];
            gA[(size_t)(16 + rb + r)*4096] = acc1[r];
          }
        }
      } else if (u < 512){
        if (t >= 1 && t <= 400){
          // decGEMM(t-1): x = [ah(t-1)(1024) | ctx(t-1)(512) | dh(t-2)(1024)]
          int did = u - 256;
          int jt = did>>3, c = did&7;
          for (int i = tid; i < 2560; i += 512){
            int p = i & 1, q = i >> 1;
            int b = q / 40, k8 = q - b*40;
            int kg = c*320 + k8*8;
            const __half* s;
            if (kg < 1024)      s = (p ? ahpL : ahpH) + b*1024 + kg;
            else if (kg < 1536) s = (p ? ctxPL : ctxPH) + b*512 + (kg-1024);
            else                s = (p ? P.dhL : P.dhH) + b*1024 + (kg-1536);
            int m = b>>4, ln = ((k8&3)<<4)|(b&15), ksl = k8>>2;
            __half* xfp = p ? xfl : xfh;
            *(int4*)(xfp + (((ksl<<1)|m)<<9) + ln*8) = *(const int4*)s;
          }
          __syncthreads();
          int jt16 = jt*8 + wid;
          f32x4 acc0 = {0.f,0.f,0.f,0.f}, acc1 = {0.f,0.f,0.f,0.f};
          for (int ksl=0; ksl<10; ksl++){
            int ks = c*10 + ksl;
            f16x8 bw = *(const f16x8*)(P.WDm + (size_t)ks*131072 + (size_t)jt16*512 + lane*8);
            f16x8 a0h = *(const f16x8*)(xfh + (ksl<<10) + lane*8);
            f16x8 a1h = *(const f16x8*)(xfh + (ksl<<10) + 512 + lane*8);
            f16x8 a0l = *(const f16x8*)(xfl + (ksl<<10) + lane*8);
            f16x8 a1l = *(const f16x8*)(xfl + (ksl<<10) + 512 + lane*8);
            acc0 = MFMA161632(a0h, bw, acc0);
            acc1 = MFMA161632(a1h, bw, acc1);
            acc0 = MFMA161632(a0l, bw, acc0);
            acc1 = MFMA161632(a1l, bw, acc1);
          }
          int colj = (jt16<<4) + (lane&15);
          int rb = (lane>>4)<<2;
          float* gD = P.gpD + (size_t)c*131072 + colj;
          #pragma unroll
          for (int r=0;r<4;r++){
            gD[(size_t)(rb + r)*4096]      = acc0[r];
            gD[(size_t)(16 + rb + r)*4096] = acc1[r];
          }
        }
      } else if (u < 556){
        if (t >= 2){
          // proj(t-2): x = [dh(t-2)(1024) | ctx(t-2)(512)]; ctx(t-2) is in ctxN buffer
          int eb = u - 512;                 // 0..43
          int b0 = (eb&3)*8;
          int row = (eb>>2)*8 + wid;        // 0..87
          bool act = (row <= 80);
          const float* wrow = (row<80) ? (P.Wproj + (size_t)row*1536) : P.Wgate;
          float acc[8];
          #pragma unroll
          for (int bi=0;bi<8;bi++) acc[bi]=0.f;
          for (int i4=tid; i4<2048; i4+=512){
            int bi=i4>>8, kk=(i4&255)<<2;
            *(float4*)(smf + bi*1024 + kk) = *(const float4*)(P.dh + (b0+bi)*1024 + kk);
          }
          __syncthreads();
          if (act){
            #pragma unroll
            for (int kq=0;kq<4;kq++){
              int k0=kq*256+lane*4;
              float4 w4 = *(const float4*)(wrow + k0);
              #pragma unroll
              for (int bi=0;bi<8;bi++){
                float4 x = *(float4*)(smf + bi*1024 + k0);
                acc[bi] += x.x*w4.x + x.y*w4.y + x.z*w4.z + x.w*w4.w;
              }
            }
          }
          __syncthreads();
          for (int i4=tid; i4<1024; i4+=512){
            int bi=i4>>7, kk=(i4&127)<<2;
            *(float4*)(smf + bi*512 + kk) = *(const float4*)(ctxN + (b0+bi)*512 + kk);
          }
          __syncthreads();
          if (act){
            #pragma unroll
            for (int kq=0;kq<2;kq++){
              int k0=kq*256+lane*4;
              float4 w4 = *(const float4*)(wrow + 1024 + k0);
              #pragma unroll
              for (int bi=0;bi<8;bi++){
                float4 x = *(float4*)(smf + bi*512 + k0);
                acc[bi] += x.x*w4.x + x.y*w4.y + x.z*w4.z + x.w*w4.w;
              }
            }
            #pragma unroll
            for (int bi=0;bi<8;bi++){
              float v = acc[bi];
              #pragma unroll
              for (int d=1; d<64; d<<=1) v += __shfl_xor(v, d, 64);
              acc[bi]=v;
            }
            if (lane==0){
              float bias = (row<80)? P.bproj[row] : P.bgate[0];
              #pragma unroll
              for (int bi=0;bi<8;bi++){
                float v = acc[bi]+bias;
                if (row<80) P.out[(size_t)(b0+bi)*32000 + row*400 + (t-2)] = v;
                else        P.out[GATE_OFF + (b0+bi)*400 + (t-2)] = v;
              }
            }
          }
        }
      } else {
        if (t < 400){
          // location conv (+pm pre-add), fp16 pm/loc
          int gw = (u-556)*8 + wid;
          int b = gw>>6, rr = gw&63, t0 = (rr>>1)*16, a = (rr&1)*64 + lane;
          float acc[16];
          #pragma unroll
          for (int tl=0;tl<16;tl++) acc[tl]=0.f;
          #pragma unroll
          for (int c=0;c<2;c++){
            const float* src = c ? P.awc : P.aw;
            float awin[46];
            #pragma unroll
            for (int i=0;i<46;i++){
              int tt = t0-15+i;
              awin[i] = (tt>=0 && tt<512) ? src[b*512+tt] : 0.f;
            }
            #pragma unroll
            for (int k=0;k<31;k++){
              float mcv = P.Mc[(c*31+k)*128 + a];
              #pragma unroll
              for (int tl=0;tl<16;tl++) acc[tl] += awin[tl + k]*mcv;
            }
          }
          #pragma unroll
          for (int tl=0;tl<16;tl++){
            size_t idx = ((size_t)b*512 + t0+tl)*128 + a;
            P.locH[idx] = __float2half(acc[tl] + (float)P.pmH[idx]);
          }
        }
      }
      __syncthreads();
    }
    grid.sync();

    // ---------------- PHASE 2 ----------------
    if (wg < 64){
      if (t < 400){
        int b = wg>>1, eh = wg&1;
        #pragma unroll
        for (int i=0;i<2;i++){
          int jj = tid + i*512;
          float gi=0.f, gf=0.f, gg=0.f, go=0.f;
          #pragma unroll
          for (int c=0;c<8;c++){
            const float* g = P.gpA + (size_t)(c*32+b)*4096;
            gi += g[jj]; gf += g[1024+jj]; gg += g[2048+jj]; go += g[3072+jj];
          }
          gi += P.bihA[jj]      + P.bhhA[jj];
          gf += P.bihA[1024+jj] + P.bhhA[1024+jj];
          gg += P.bihA[2048+jj] + P.bhhA[2048+jj];
          go += P.bihA[3072+jj] + P.bhhA[3072+jj];
          float c2 = sigf(gf)*acp[b*1024+jj] + sigf(gi)*tanhfast(gg);
          float hh = sigf(go)*tanhfast(c2);
          if (eh==0){
            acn[b*1024+jj] = c2;
            __half hhh = __float2half(hh);
            ahnH[b*1024+jj] = hhh;
            ahnL[b*1024+jj] = __float2half(hh - __half2float(hhh));
          }
          smf[jj] = hh;
        }
        __syncthreads();
        // q = ah @ Wq^T (a-major fp16 Wq)
        {
          int a = tid&127, kq = tid>>7;
          const __half* wr = P.WqTh + a*1024 + kq*256;
          const float* xr = smf + kq*256;
          float p = 0.f;
          for (int k2=0; k2<256; k2+=8){
            f16x8 wv = *(const f16x8*)(wr + k2);
            float4 x0 = *(const float4*)(xr + k2);
            float4 x1 = *(const float4*)(xr + k2 + 4);
            p += x0.x*(float)wv[0] + x0.y*(float)wv[1] + x0.z*(float)wv[2] + x0.w*(float)wv[3]
               + x1.x*(float)wv[4] + x1.y*(float)wv[5] + x1.z*(float)wv[6] + x1.w*(float)wv[7];
          }
          smf[1024 + kq*128 + a] = p;
        }
        __syncthreads();
        if (tid < 128) smf[1536+tid] = smf[1024+tid] + smf[1152+tid] + smf[1280+tid] + smf[1408+tid];
        __syncthreads();
        // scores: thread = t-position (fp16 loc)
        int s = tid;
        const __half* lrow = P.locH + ((size_t)b*512 + s)*128;
        float sc = 0.f;
        #pragma unroll
        for (int a=0; a<128; a+=4){
          __half2 h0 = *(const __half2*)(lrow + a);
          __half2 h1 = *(const __half2*)(lrow + a + 2);
          float2 l0 = __half22float2(h0);
          float2 l1 = __half22float2(h1);
          float4 wv = *(const float4*)(P.Wsc + a);
          sc += wv.x*tanhfast(smf[1536+a+0]+l0.x) + wv.y*tanhfast(smf[1536+a+1]+l0.y)
              + wv.z*tanhfast(smf[1536+a+2]+l1.x) + wv.w*tanhfast(smf[1536+a+3]+l1.y);
        }
        float ex = __expf(sc + P.bsc[0]);   // tanh-bounded: safe without max-sub
        float exs = ex;
        #pragma unroll
        for (int d=1; d<64; d<<=1) exs += __shfl_xor(exs, d, 64);
        if (lane==0) smf[2176+wid] = exs;
        __syncthreads();
        float den = smf[2176]+smf[2177]+smf[2178]+smf[2179]+smf[2180]+smf[2181]+smf[2182]+smf[2183];
        float w = ex / den;
        if (eh==0){
          P.aw[b*512+s] = w;
          P.awc[b*512+s] += w;
          P.out[ALIGN_OFF + (size_t)b*204800 + (size_t)t*512 + s] = w;
        }
        smf[1664+s] = w;
        __syncthreads();
        // ctx half: e in [eh*256, eh*256+256)
        int e0 = eh<<8;
        float a4[4] = {0.f,0.f,0.f,0.f};
        const __half* mb = P.memH + (size_t)b*262144 + e0 + lane*4;
        for (int t2 = wid*64; t2 < wid*64+64; t2++){
          float wv = smf[1664+t2];
          f16x4 mv = *(const f16x4*)(mb + (size_t)t2*512);
          a4[0] += wv*(float)mv[0]; a4[1] += wv*(float)mv[1];
          a4[2] += wv*(float)mv[2]; a4[3] += wv*(float)mv[3];
        }
        *(float4*)(&smf[2304 + wid*256 + lane*4]) = make_float4(a4[0],a4[1],a4[2],a4[3]);
        __syncthreads();
        if (tid < 256){
          float cv = 0.f;
          #pragma unroll
          for (int u8=0;u8<8;u8++) cv += smf[2304 + u8*256 + tid];
          int e = e0 + tid;
          ctxN[b*512+e] = cv;
          __half ch = __float2half(cv);
          ctxNH[b*512+e] = ch;
          ctxNL[b*512+e] = __float2half(cv - __half2float(ch));
        }
      }
    } else if (wg < 96){
      if (t >= 1 && t <= 400){
        // dec activation for step t-1 (8 partials)
        int b = wg - 64;
        #pragma unroll
        for (int i=0;i<2;i++){
          int jj = tid + i*512;
          float gi=0.f, gf=0.f, gg=0.f, go=0.f;
          #pragma unroll
          for (int c=0;c<8;c++){
            const float* g = P.gpD + (size_t)(c*32+b)*4096;
            gi += g[jj]; gf += g[1024+jj]; gg += g[2048+jj]; go += g[3072+jj];
          }
          gi += P.bihD[jj]      + P.bhhD[jj];
          gf += P.bihD[1024+jj] + P.bhhD[1024+jj];
          gg += P.bihD[2048+jj] + P.bhhD[2048+jj];
          go += P.bihD[3072+jj] + P.bhhD[3072+jj];
          float c2 = sigf(gf)*P.dc[b*1024+jj] + sigf(gi)*tanhfast(gg);
          float hh = sigf(go)*tanhfast(c2);
          P.dc[b*1024+jj] = c2;
          P.dh[b*1024+jj] = hh;
          __half hhh = __float2half(hh);
          P.dhH[b*1024+jj] = hhh;
          P.dhL[b*1024+jj] = __float2half(hh - __half2float(hhh));
        }
      }
    }
    grid.sync();
  }
}

// ================= fallback per-step kernels (identical to Round-2) =================
__global__ __launch_bounds__(512) void k_AD(Ptrs P, int t, int nG, int nConv, int nDec, int nProj){
  __shared__ __align__(16) __half xf[2][10240];
  int bid = blockIdx.x, tid = threadIdx.x;
  int wid = tid>>6, lane = tid&63;

  if (bid < nG){
    int jt = bid>>3, c = bid&7;
    for (int i = tid; i < 1792; i += 512){
      int p = i & 1, q = i >> 1;
      int b = q / 28, k8 = q - b*28;
      int kg = c*224 + k8*8;
      const __half* s;
      if (kg < 256)      s = (p ? P.preL : P.preH) + (size_t)(t*32+b)*256 + kg;
      else if (kg < 768) s = (p ? P.ctxPL : P.ctxPH) + b*512 + (kg-256);
      else               s = (p ? P.ahpL : P.ahpH) + b*1024 + (kg-768);
      int m = b>>4, ln = ((k8&3)<<4)|(b&15), ksl = k8>>2;
      *(int4*)(&xf[p][(((ksl<<1)|m)<<9) + ln*8]) = *(const int4*)s;
    }
    __syncthreads();
    int jt16 = jt*8 + wid;
    f32x4 acc0 = {0.f,0.f,0.f,0.f}, acc1 = {0.f,0.f,0.f,0.f};
    for (int ksl=0; ksl<7; ksl++){
      int ks = c*7 + ksl;
      f16x8 bw = *(const f16x8*)(P.WAm + (size_t)ks*131072 + (size_t)jt16*512 + lane*8);
      f16x8 a0h = *(const f16x8*)(&xf[0][(ksl<<10) + lane*8]);
      f16x8 a1h = *(const f16x8*)(&xf[0][(ksl<<10) + 512 + lane*8]);
      f16x8 a0l = *(const f16x8*)(&xf[1][(ksl<<10) + lane*8]);
      f16x8 a1l = *(const f16x8*)(&xf[1][(ksl<<10) + 512 + lane*8]);
      acc0 = MFMA161632(a0h, bw, acc0);
      acc1 = MFMA161632(a1h, bw, acc1);
      acc0 = MFMA161632(a0l, bw, acc0);
      acc1 = MFMA161632(a1l, bw, acc1);
    }
    int colj = (jt16<<4) + (lane&15);
    int rb = (lane>>4)<<2;
    float* gA = P.gpA + (size_t)c*131072 + colj;
    #pragma unroll
    for (int r=0;r<4;r++){
      gA[(size_t)(rb + r)*4096]      = acc0[r];
      gA[(size_t)(16 + rb + r)*4096] = acc1[r];
    }
  } else if (bid < nG+nConv){
    int gw = (bid-nG)*8 + wid;
    int b = gw>>6, rr = gw&63, t0 = (rr>>1)*16, a = (rr&1)*64 + lane;
    float acc[16];
    #pragma unroll
    for (int tl=0;tl<16;tl++) acc[tl]=0.f;
    #pragma unroll
    for (int c=0;c<2;c++){
      const float* src = c ? P.awc : P.aw;
      float awin[46];
      #pragma unroll
      for (int i=0;i<46;i++){
        int tt = t0-15+i;
        awin[i] = (tt>=0 && tt<512) ? src[b*512+tt] : 0.f;
      }
      #pragma unroll
      for (int k=0;k<31;k++){
        float mcv = P.Mc[(c*31+k)*128 + a];
        #pragma unroll
        for (int tl=0;tl<16;tl++) acc[tl] += awin[tl + k]*mcv;
      }
    }
    #pragma unroll
    for (int tl=0;tl<16;tl++){
      size_t idx = ((size_t)b*512 + t0+tl)*128 + a;
      P.locH[idx] = __float2half(acc[tl] + (float)P.pmH[idx]);
    }
  } else if (bid < nG+nConv+nDec){
    int did = bid - nG - nConv;
    int jt = did>>3, c = did&7;
    for (int i = tid; i < 2560; i += 512){
      int p = i & 1, q = i >> 1;
      int b = q / 40, k8 = q - b*40;
      int kg = c*320 + k8*8;
      const __half* s;
      if (kg < 1024)      s = (p ? P.ahpL : P.ahpH) + b*1024 + kg;
      else if (kg < 1536) s = (p ? P.ctxPL : P.ctxPH) + b*512 + (kg-1024);
      else                s = (p ? P.dhL : P.dhH) + b*1024 + (kg-1536);
      int m = b>>4, ln = ((k8&3)<<4)|(b&15), ksl = k8>>2;
      *(int4*)(&xf[p][(((ksl<<1)|m)<<9) + ln*8]) = *(const int4*)s;
    }
    __syncthreads();
    int jt16 = jt*8 + wid;
    f32x4 acc0 = {0.f,0.f,0.f,0.f}, acc1 = {0.f,0.f,0.f,0.f};
    for (int ksl=0; ksl<10; ksl++){
      int ks = c*10 + ksl;
      f16x8 bw = *(const f16x8*)(P.WDm + (size_t)ks*131072 + (size_t)jt16*512 + lane*8);
      f16x8 a0h = *(const f16x8*)(&xf[0][(ksl<<10) + lane*8]);
      f16x8 a1h = *(const f16x8*)(&xf[0][(ksl<<10) + 512 + lane*8]);
      f16x8 a0l = *(const f16x8*)(&xf[1][(ksl<<10) + lane*8]);
      f16x8 a1l = *(const f16x8*)(&xf[1][(ksl<<10) + 512 + lane*8]);
      acc0 = MFMA161632(a0h, bw, acc0);
      acc1 = MFMA161632(a1h, bw, acc1);
      acc0 = MFMA161632(a0l, bw, acc0);
      acc1 = MFMA161632(a1l, bw, acc1);
    }
    int colj = (jt16<<4) + (lane&15);
    int rb = (lane>>4)<<2;
    float* gD = P.gpD + (size_t)c*131072 + colj;
    #pragma unroll
    for (int r=0;r<4;r++){
      gD[(size_t)(rb + r)*4096]      = acc0[r];
      gD[(size_t)(16 + rb + r)*4096] = acc1[r];
    }
  } else {
    float* smf = (float*)xf;
    int eb = bid - nG - nConv - nDec;
    int b0 = (eb&3)*8;
    int row = (eb>>2)*8 + wid;
    bool act = (row <= 80);
    const float* wrow = (row<80) ? (P.Wproj + (size_t)row*1536) : P.Wgate;
    float acc[8];
    #pragma unroll
    for (int bi=0;bi<8;bi++) acc[bi]=0.f;
    for (int i4=tid; i4<2048; i4+=512){
      int bi=i4>>8, kk=(i4&255)<<2;
      *(float4*)(smf + bi*1024 + kk) = *(const float4*)(P.dh + (b0+bi)*1024 + kk);
    }
    __syncthreads();
    if (act){
      #pragma unroll
      for (int kq=0;kq<4;kq++){
        int k0=kq*256+lane*4;
        float4 w4 = *(const float4*)(wrow + k0);
        #pragma unroll
        for (int bi=0;bi<8;bi++){
          float4 x = *(float4*)(smf + bi*1024 + k0);
          acc[bi] += x.x*w4.x + x.y*w4.y + x.z*w4.z + x.w*w4.w;
        }
      }
    }
    __syncthreads();
    for (int i4=tid; i4<1024; i4+=512){
      int bi=i4>>7, kk=(i4&127)<<2;
      *(float4*)(smf + bi*512 + kk) = *(const float4*)(P.ctxN + (b0+bi)*512 + kk);
    }
    __syncthreads();
    if (act){
      #pragma unroll
      for (int kq=0;kq<2;kq++){
        int k0=kq*256+lane*4;
        float4 w4 = *(const float4*)(wrow + 1024 + k0);
        #pragma unroll
        for (int bi=0;bi<8;bi++){
          float4 x = *(float4*)(smf + bi*512 + k0);
          acc[bi] += x.x*w4.x + x.y*w4.y + x.z*w4.z + x.w*w4.w;
        }
      }
      #pragma unroll
      for (int bi=0;bi<8;bi++){
        float v = acc[bi];
        #pragma unroll
        for (int d=1; d<64; d<<=1) v += __shfl_xor(v, d, 64);
        acc[bi]=v;
      }
      if (lane==0){
        float bias = (row<80)? P.bproj[row] : P.bgate[0];
        #pragma unroll
        for (int bi=0;bi<8;bi++){
          float v = acc[bi]+bias;
          if (row<80) P.out[(size_t)(b0+bi)*32000 + row*400 + (t-2)] = v;
          else        P.out[GATE_OFF + (b0+bi)*400 + (t-2)] = v;
        }
      }
    }
  }
}

__global__ __launch_bounds__(512) void k_BC(Ptrs P, int t, int nAtt, int nDact){
  __shared__ float sm[4608];
  int bid = blockIdx.x, tid = threadIdx.x;
  int wid = tid>>6, lane = tid&63;
  if (bid < nAtt){
    int b = bid>>1, eh = bid&1;
    #pragma unroll
    for (int i=0;i<2;i++){
      int jj = tid + i*512;
      float gi=0.f, gf=0.f, gg=0.f, go=0.f;
      #pragma unroll
      for (int c=0;c<8;c++){
        const float* g = P.gpA + (size_t)(c*32+b)*4096;
        gi += g[jj]; gf += g[1024+jj]; gg += g[2048+jj]; go += g[3072+jj];
      }
      gi += P.bihA[jj]      + P.bhhA[jj];
      gf += P.bihA[1024+jj] + P.bhhA[1024+jj];
      gg += P.bihA[2048+jj] + P.bhhA[2048+jj];
      go += P.bihA[3072+jj] + P.bhhA[3072+jj];
      float c2 = sigf(gf)*P.acp[b*1024+jj] + sigf(gi)*tanhfast(gg);
      float hh = sigf(go)*tanhfast(c2);
      if (eh==0){
        P.acn[b*1024+jj] = c2;
        __half hhh = __float2half(hh);
        P.ahnH[b*1024+jj] = hhh;
        P.ahnL[b*1024+jj] = __float2half(hh - __half2float(hhh));
      }
      sm[jj] = hh;
    }
    __syncthreads();
    {
      int a = tid&127, kq = tid>>7;
      const __half* wr = P.WqTh + a*1024 + kq*256;
      const float* xr = sm + kq*256;
      float p = 0.f;
      for (int k2=0; k2<256; k2+=8){
        f16x8 wv = *(const f16x8*)(wr + k2);
        float4 x0 = *(const float4*)(xr + k2);
        float4 x1 = *(const float4*)(xr + k2 + 4);
        p += x0.x*(float)wv[0] + x0.y*(float)wv[1] + x0.z*(float)wv[2] + x0.w*(float)wv[3]
           + x1.x*(float)wv[4] + x1.y*(float)wv[5] + x1.z*(float)wv[6] + x1.w*(float)wv[7];
      }
      sm[1024 + kq*128 + a] = p;
    }
    __syncthreads();
    if (tid < 128) sm[1536+tid] = sm[1024+tid] + sm[1152+tid] + sm[1280+tid] + sm[1408+tid];
    __syncthreads();
    int s = tid;
    const __half* lrow = P.locH + ((size_t)b*512 + s)*128;
    float sc = 0.f;
    #pragma unroll
    for (int a=0; a<128; a+=4){
      __half2 h0 = *(const __half2*)(lrow + a);
      __half2 h1 = *(const __half2*)(lrow + a + 2);
      float2 l0 = __half22float2(h0);
      float2 l1 = __half22float2(h1);
      float4 wv = *(const float4*)(P.Wsc + a);
      sc += wv.x*tanhfast(sm[1536+a+0]+l0.x) + wv.y*tanhfast(sm[1536+a+1]+l0.y)
          + wv.z*tanhfast(sm[1536+a+2]+l1.x) + wv.w*tanhfast(sm[1536+a+3]+l1.y);
    }
    float ex = __expf(sc + P.bsc[0]);
    float exs = ex;
    #pragma unroll
    for (int d=1; d<64; d<<=1) exs += __shfl_xor(exs, d, 64);
    if (lane==0) sm[2176+wid] = exs;
    __syncthreads();
    float den = sm[2176]+sm[2177]+sm[2178]+sm[2179]+sm[2180]+sm[2181]+sm[2182]+sm[2183];
    float w = ex / den;
    if (eh==0){
      P.aw[b*512+s] = w;
      P.awc[b*512+s] += w;
      P.out[ALIGN_OFF + (size_t)b*204800 + (size_t)t*512 + s] = w;
    }
    sm[1664+s] = w;
    __syncthreads();
    int e0 = eh<<8;
    float a4[4] = {0.f,0.f,0.f,0.f};
    const __half* mb = P.memH + (size_t)b*262144 + e0 + lane*4;
    for (int t2 = wid*64; t2 < wid*64+64; t2++){
      float wv = sm[1664+t2];
      f16x4 mv = *(const f16x4*)(mb + (size_t)t2*512);
      a4[0] += wv*(float)mv[0]; a4[1] += wv*(float)mv[1];
      a4[2] += wv*(float)mv[2]; a4[3] += wv*(float)mv[3];
    }
    *(float4*)(&sm[2304 + wid*256 + lane*4]) = make_float4(a4[0],a4[1],a4[2],a4[3]);
    __syncthreads();
    if (tid < 256){
      float cv = 0.f;
      #pragma unroll
      for (int u=0;u<8;u++) cv += sm[2304 + u*256 + tid];
      int e = e0 + tid;
      P.ctxN[b*512+e] = cv;
      __half ch = __float2half(cv);
      P.ctxNH[b*512+e] = ch;
      P.ctxNL[b*512+e] = __float2half(cv - __half2float(ch));
    }
  } else {
    int b = bid - nAtt;
    #pragma unroll
    for (int i=0;i<2;i++){
      int jj = tid + i*512;
      float gi=0.f, gf=0.f, gg=0.f, go=0.f;
      #pragma unroll
      for (int c=0;c<8;c++){
        const float* g = P.gpD + (size_t)(c*32+b)*4096;
        gi += g[jj]; gf += g[1024+jj]; gg += g[2048+jj]; go += g[3072+jj];
      }
      gi += P.bihD[jj]      + P.bhhD[jj];
      gf += P.bihD[1024+jj] + P.bhhD[1024+jj];
      gg += P.bihD[2048+jj] + P.bhhD[2048+jj];
      go += P.bihD[3072+jj] + P.bhhD[3072+jj];
      float c2 = sigf(gf)*P.dc[b*1024+jj] + sigf(gi)*tanhfast(gg);
      float hh = sigf(go)*tanhfast(c2);
      P.dc[b*1024+jj] = c2;
      P.dh[b*1024+jj] = hh;
      __half hhh = __float2half(hh);
      P.dhH[b*1024+jj] = hhh;
      P.dhL[b*1024+jj] = __float2half(hh - __half2float(hhh));
    }
  }
}

// ---------------- host ----------------
extern "C" void kernel_launch(void* const* d_in, const int* in_sizes, int n_in,
                              void* d_out, int out_size, void* d_ws, size_t ws_size,
                              hipStream_t stream) {
  Ptrs P;
  P.mem   = (const float*)d_in[0];  P.dec   = (const float*)d_in[1];
  P.Wpre1 = (const float*)d_in[2];  P.Wpre2 = (const float*)d_in[3];
  P.WihA  = (const float*)d_in[4];  P.WhhA  = (const float*)d_in[5];
  P.bihA  = (const float*)d_in[6];  P.bhhA  = (const float*)d_in[7];
  P.WihD  = (const float*)d_in[8];  P.WhhD  = (const float*)d_in[9];
  P.bihD  = (const float*)d_in[10]; P.bhhD  = (const float*)d_in[11];
  P.Wq    = (const float*)d_in[12]; P.Wm    = (const float*)d_in[13];
  P.Wsc   = (const float*)d_in[14]; P.bsc   = (const float*)d_in[15];
  P.Wlc   = (const float*)d_in[16]; P.Wld   = (const float*)d_in[17];
  P.Wproj = (const float*)d_in[18]; P.bproj = (const float*)d_in[19];
  P.Wgate = (const float*)d_in[20]; P.bgate = (const float*)d_in[21];
  P.out = (float*)d_out;

  float* ws = (float*)d_ws;
  size_t o = 0;
  P.pmH  = (__half*)(ws + o); o += 1048576;   // [32][512][128] fp16
  P.preH = (__half*)(ws + o); o += 1638400;   // [12800][256] fp16 hi
  P.preL = (__half*)(ws + o); o += 1638400;   // fp16 lo
  P.locH = (__half*)(ws + o); o += 1048576;   // fp16
  P.WqTh = (__half*)(ws + o); o += 65536;     // fp16 [128][1024] a-major
  P.Mc   = ws + o; o += 8192;
  P.W1T  = ws + o; o += 20480;
  P.W2T  = ws + o; o += 65536;
  P.WmT  = ws + o; o += 65536;
  P.gpA  = ws + o; o += 1048576;              // [8][32][4096] fp32
  P.gpD  = ws + o; o += 1048576;
  float* stateBase = ws + o;
  float* AC[2]; AC[0] = ws + o; o += 32768; AC[1] = ws + o; o += 32768;
  P.dh  = ws + o; o += 32768;
  P.dc  = ws + o; o += 32768;
  float* CT[2]; CT[0] = ws + o; o += 16384; CT[1] = ws + o; o += 16384;
  P.aw  = ws + o; o += 16384;
  P.awc = ws + o; o += 16384;
  __half* AHH[2]; AHH[0]=(__half*)(ws+o); o+=16384; AHH[1]=(__half*)(ws+o); o+=16384;
  __half* AHL[2]; AHL[0]=(__half*)(ws+o); o+=16384; AHL[1]=(__half*)(ws+o); o+=16384;
  __half* CTH[2]; CTH[0]=(__half*)(ws+o); o+=8192;  CTH[1]=(__half*)(ws+o); o+=8192;
  __half* CTL[2]; CTL[0]=(__half*)(ws+o); o+=8192;  CTL[1]=(__half*)(ws+o); o+=8192;
  P.dhH = (__half*)(ws+o); o += 16384;
  P.dhL = (__half*)(ws+o); o += 16384;
  int stateN = (int)((ws + o) - stateBase);
  P.memH = (__half*)(ws + o); o += 4194304;   // [32][512][512] fp16
  P.WAm  = (__half*)(ws + o); o += 3670016;   // [56][256][64][8] fp16 frag
  P.WDm  = (__half*)(ws + o); o += 5242880;   // [80][256][64][8] fp16 frag
  P.p1   = (float*)P.WAm;                     // prologue scratch aliases WAm region

  P.AC2[0]=AC[0]; P.AC2[1]=AC[1]; P.CT2[0]=CT[0]; P.CT2[1]=CT[1];
  P.AHH2[0]=AHH[0]; P.AHH2[1]=AHH[1]; P.AHL2[0]=AHL[0]; P.AHL2[1]=AHL[1];
  P.CTH2[0]=CTH[0]; P.CTH2[1]=CTH[1]; P.CTL2[0]=CTL[0]; P.CTL2[1]=CTL[1];
  P.acp = AC[0]; P.acn = AC[1];
  P.ctxP = CT[0]; P.ctxN = CT[1];
  P.ahpH = AHH[0]; P.ahnH = AHH[1]; P.ahpL = AHL[0]; P.ahnL = AHL[1];
  P.ctxPH = CTH[0]; P.ctxNH = CTH[1]; P.ctxPL = CTL[0]; P.ctxNL = CTL[1];

  hipLaunchKernelGGL(k_init, dim3((stateN+255)/256), dim3(256), 0, stream, stateBase, stateN);
  hipLaunchKernelGGL(k_memh, dim3(8192), dim3(1024), 0, stream, P);
  hipLaunchKernelGGL(k_xform, dim3(1135), dim3(256), 0, stream, P);
  hipLaunchKernelGGL(k_pn1, dim3(1600), dim3(256), 0, stream, P);
  hipLaunchKernelGGL(k_pn2, dim3(1600), dim3(256), 0, stream, P);
  hipLaunchKernelGGL(k_pm,  dim3(2048), dim3(256), 0, stream, P);
  hipLaunchKernelGGL(k_tA,  dim3(3584), dim3(256), 0, stream, P);
  hipLaunchKernelGGL(k_tD,  dim3(5120), dim3(256), 0, stream, P);

  // persistent cooperative loop; fall back to per-step launches if unsupported
  Ptrs Pk = P;
  void* kargs[] = { (void*)&Pk };
  hipError_t ce = hipLaunchCooperativeKernel((const void*)k_loop, dim3(512), dim3(512),
                                             kargs, 0, stream);
  if (ce != hipSuccess){
    (void)hipGetLastError();  // clear error state
    for (int t=0; t<400; t++){
      Ptrs Q = P;
      Q.acp = AC[t&1];     Q.acn = AC[(t+1)&1];
      Q.ctxP = CT[t&1];    Q.ctxN = CT[(t+1)&1];
      Q.ahpH = AHH[t&1];   Q.ahnH = AHH[(t+1)&1];
      Q.ahpL = AHL[t&1];   Q.ahnL = AHL[(t+1)&1];
      Q.ctxPH = CTH[t&1];  Q.ctxNH = CTH[(t+1)&1];
      Q.ctxPL = CTL[t&1];  Q.ctxNL = CTL[(t+1)&1];
      int nDec  = t ? 256 : 0;
      int nProj = (t>=2) ? 44 : 0;
      int nDact = t ? 32 : 0;
      hipLaunchKernelGGL(k_AD, dim3(512+nDec+nProj), dim3(512), 0, stream, Q, t, 256, 256, nDec, nProj);
      hipLaunchKernelGGL(k_BC, dim3(64+nDact), dim3(512), 0, stream, Q, t, 64, nDact);
    }
    {
      int t = 400;
      Ptrs Q = P;
      Q.acp = AC[t&1];     Q.acn = AC[(t+1)&1];
      Q.ctxP = CT[t&1];    Q.ctxN = CT[(t+1)&1];
      Q.ahpH = AHH[t&1];   Q.ahnH = AHH[(t+1)&1];
      Q.ahpL = AHL[t&1];   Q.ahnL = AHL[(t+1)&1];
      Q.ctxPH = CTH[t&1];  Q.ctxNH = CTH[(t+1)&1];
      Q.ctxPL = CTL[t&1];  Q.ctxNL = CTL[(t+1)&1];
      hipLaunchKernelGGL(k_AD, dim3(256+44), dim3(512), 0, stream, Q, t, 0, 0, 256, 44);
      hipLaunchKernelGGL(k_BC, dim3(32), dim3(512), 0, stream, Q, t, 0, 32);
    }
    {
      int t = 401;
      Ptrs Q = P;
      Q.acp = AC[t&1];     Q.acn = AC[(t+1)&1];
      Q.ctxP = CT[t&1];    Q.ctxN = CT[(t+1)&1];
      Q.ahpH = AHH[t&1];   Q.ahnH = AHH[(t+1)&1];
      Q.ahpL = AHL[t&1];   Q.ahnL = AHL[(t+1)&1];
      Q.ctxPH = CTH[t&1];  Q.ctxNH = CTH[(t+1)&1];
      Q.ctxPL = CTL[t&1];  Q.ctxNL = CTL[(t+1)&1];
      hipLaunchKernelGGL(k_AD, dim3(44), dim3(512), 0, stream, Q, t, 0, 0, 0, 44);
    }
  }
}

// Round 4
// 20604.544 us; speedup vs baseline: 4.6861x; 4.6861x over previous
//
#include <hip/hip_runtime.h>
#include <hip/hip_fp16.h>

// B=32, T=512, E=512, TDEC=400, NMEL=80, RNN=1024, PRE=256, ADIM=128, KS=31
// outputs: mel [32][80][400] | gate [32][400] | align [32][400][512]
#define GATE_OFF  1024000
#define ALIGN_OFF 1036800

typedef _Float16 f16x8 __attribute__((ext_vector_type(8)));
typedef float f32x4 __attribute__((ext_vector_type(4)));
#define MFMA161632(a,b,c) __builtin_amdgcn_mfma_f32_16x16x32_f16(a,b,c,0,0,0)

struct Ptrs {
  const float *mem, *dec, *Wpre1, *Wpre2, *WihA, *WhhA, *bihA, *bhhA,
              *WihD, *WhhD, *bihD, *bhhD, *Wq, *Wm, *Wsc, *bsc,
              *Wlc, *Wld, *Wproj, *bproj, *Wgate, *bgate;
  float *out;
  float *Mc, *W1T, *W2T, *WmT, *p1, *gpA, *gpD;
  __half *pmH, *locH, *WqTh, *memH, *WAm, *WDm, *preH, *preL;
  float *acp, *acn, *dh, *dc;
  float *awcB, *exU, *ctxU, *den;   // awcB[2][32][512] | exU[2][32][512] | ctxU[2][2][32][512] | den[2][32][2]
  __half *ahpH, *ahpL, *ahnH, *ahnL, *dhH, *dhL;
};

__device__ __forceinline__ float rcpf(float x){ return __builtin_amdgcn_rcpf(x); }
__device__ __forceinline__ float sigf(float x){
  x = fminf(fmaxf(x,-30.f),30.f);
  return rcpf(1.f+__expf(-x));
}
__device__ __forceinline__ float tanhfast(float x){
  x = fminf(fmaxf(x,-15.f),15.f);
  float e = __expf(2.f*x);
  return (e-1.f)*rcpf(e+1.f);
}

__global__ void k_init(float* p, int n){
  int i = blockIdx.x*256 + threadIdx.x;
  if (i < n) p[i] = 0.f;
}

__global__ __launch_bounds__(1024) void k_memh(Ptrs P){
  int i = blockIdx.x*1024 + threadIdx.x;
  if (i < 8388608) P.memH[i] = __float2half(P.mem[i]);
}

__global__ void k_xform(Ptrs P){
  int i = blockIdx.x*256 + threadIdx.x;
  if (i < 20480){ int k=i>>8, p=i&255; P.W1T[i] = P.Wpre1[p*80 + k]; return; }
  i -= 20480;
  if (i < 65536){ int k=i>>8, p=i&255; P.W2T[i] = P.Wpre2[p*256 + k]; return; }
  i -= 65536;
  if (i < 131072){ P.WqTh[i] = __float2half(P.Wq[i]); return; }  // a-major copy [128][1024]
  i -= 131072;
  if (i < 65536){ int e=i>>7, a=i&127; P.WmT[i] = P.Wm[a*512 + e]; return; }
  i -= 65536;
  if (i < 7936){
    int c = i/3968, r = i%3968, k = r>>7, a = r&127;
    float s = 0.f;
    for (int f=0; f<31; f++) s += P.Wld[a*31+f]*P.Wlc[f*62 + c*31 + k];
    P.Mc[i] = s;
    return;
  }
  i -= 7936;
  if (i < 64) P.den[64 + i] = 0.5f;   // den parity-1 init: sums to 1 -> ctx(-1)=0, aw(-1)=0
}

// att weights -> MFMA B-fragment layout, fp16.
__global__ __launch_bounds__(256) void k_tA(Ptrs P){
  int idx = blockIdx.x*256 + threadIdx.x;          // [0, 917504)
  int lane = idx&63, jt16 = (idx>>6)&255, ks = idx>>14;   // ks<56
  int kb = ks*32 + ((lane>>4)<<3);
  int j = (jt16<<4) + (lane&15);
  const float* src;
  if (kb < 768) src = P.WihA + (size_t)j*768 + kb;
  else          src = P.WhhA + (size_t)j*1024 + (kb-768);
  float4 v0 = *(const float4*)(src);
  float4 v1 = *(const float4*)(src+4);
  union { int4 i4; __half h[8]; } u;
  u.h[0]=__float2half(v0.x); u.h[1]=__float2half(v0.y);
  u.h[2]=__float2half(v0.z); u.h[3]=__float2half(v0.w);
  u.h[4]=__float2half(v1.x); u.h[5]=__float2half(v1.y);
  u.h[6]=__float2half(v1.z); u.h[7]=__float2half(v1.w);
  *(int4*)(P.WAm + (size_t)idx*8) = u.i4;
}
__global__ __launch_bounds__(256) void k_tD(Ptrs P){
  int idx = blockIdx.x*256 + threadIdx.x;          // [0, 1310720)
  int lane = idx&63, jt16 = (idx>>6)&255, ks = idx>>14;   // ks<80
  int kb = ks*32 + ((lane>>4)<<3);
  int j = (jt16<<4) + (lane&15);
  const float* src;
  if (kb < 1536) src = P.WihD + (size_t)j*1536 + kb;
  else           src = P.WhhD + (size_t)j*1024 + (kb-1536);
  float4 v0 = *(const float4*)(src);
  float4 v1 = *(const float4*)(src+4);
  union { int4 i4; __half h[8]; } u;
  u.h[0]=__float2half(v0.x); u.h[1]=__float2half(v0.y);
  u.h[2]=__float2half(v0.z); u.h[3]=__float2half(v0.w);
  u.h[4]=__float2half(v1.x); u.h[5]=__float2half(v1.y);
  u.h[6]=__float2half(v1.z); u.h[7]=__float2half(v1.w);
  *(int4*)(P.WDm + (size_t)idx*8) = u.i4;
}

__global__ __launch_bounds__(256) void k_pn1(Ptrs P){
  __shared__ __align__(16) float pinL[8*80];
  int bid = blockIdx.x, tid = threadIdx.x;
  int r0 = bid*8;
  for (int i=tid; i<640; i+=256){
    int bi = i/80, m = i%80;
    int row = r0+bi, tt = row>>5, b = row&31;
    pinL[bi*80+m] = (tt==0) ? 0.f : P.dec[(size_t)b*32000 + m*400 + (tt-1)];
  }
  __syncthreads();
  int p = tid;
  float acc[8];
  #pragma unroll
  for (int bi=0;bi<8;bi++) acc[bi]=0.f;
  #pragma unroll
  for (int kq=0; kq<20; kq++){
    int k0 = kq*4;
    float w0 = P.W1T[(k0+0)*256+p], w1 = P.W1T[(k0+1)*256+p];
    float w2 = P.W1T[(k0+2)*256+p], w3 = P.W1T[(k0+3)*256+p];
    #pragma unroll
    for (int bi=0;bi<8;bi++){
      float4 x = *(float4*)(pinL + bi*80 + k0);
      acc[bi] += x.x*w0 + x.y*w1 + x.z*w2 + x.w*w3;
    }
  }
  #pragma unroll
  for (int bi=0;bi<8;bi++) P.p1[(size_t)(r0+bi)*256 + p] = fmaxf(acc[bi],0.f);
}

__global__ __launch_bounds__(256) void k_pn2(Ptrs P){
  __shared__ __align__(16) float xL[8*256];
  int bid = blockIdx.x, tid = threadIdx.x;
  size_t r0 = (size_t)bid*8;
  for (int i4=tid; i4<512; i4+=256)
    *(float4*)(xL + i4*4) = *(const float4*)(P.p1 + r0*256 + i4*4);
  __syncthreads();
  int p = tid;
  float acc[8];
  #pragma unroll
  for (int bi=0;bi<8;bi++) acc[bi]=0.f;
  for (int kq=0; kq<64; kq++){
    int k0 = kq*4;
    float w0 = P.W2T[(k0+0)*256+p], w1 = P.W2T[(k0+1)*256+p];
    float w2 = P.W2T[(k0+2)*256+p], w3 = P.W2T[(k0+3)*256+p];
    #pragma unroll
    for (int bi=0;bi<8;bi++){
      float4 x = *(float4*)(xL + bi*256 + k0);
      acc[bi] += x.x*w0 + x.y*w1 + x.z*w2 + x.w*w3;
    }
  }
  #pragma unroll
  for (int bi=0;bi<8;bi++){
    float v = fmaxf(acc[bi],0.f);
    __half h = __float2half(v);
    size_t off = (r0+bi)*256 + p;
    P.preH[off] = h;
    P.preL[off] = __float2half(v - __half2float(h));
  }
}

__global__ __launch_bounds__(256) void k_pm(Ptrs P){
  __shared__ __align__(16) float memL[8*512];
  int bid = blockIdx.x, tid = threadIdx.x;
  size_t r0 = (size_t)bid*8;
  for (int i4=tid; i4<1024; i4+=256)
    *(float4*)(memL + i4*4) = *(const float4*)(P.mem + r0*512 + i4*4);
  __syncthreads();
  int a = tid&127, rq = tid>>7;
  float acc[4];
  #pragma unroll
  for (int ri=0;ri<4;ri++) acc[ri]=0.f;
  for (int kq=0; kq<128; kq++){
    int k0 = kq*4;
    float w0 = P.WmT[(k0+0)*128+a], w1 = P.WmT[(k0+1)*128+a];
    float w2 = P.WmT[(k0+2)*128+a], w3 = P.WmT[(k0+3)*128+a];
    #pragma unroll
    for (int ri=0;ri<4;ri++){
      float4 x = *(float4*)(memL + (rq*4+ri)*512 + k0);
      acc[ri] += x.x*w0 + x.y*w1 + x.z*w2 + x.w*w3;
    }
  }
  #pragma unroll
  for (int ri=0;ri<4;ri++) P.pmH[(r0 + rq*4+ri)*128 + a] = __float2half(acc[ri]);
}

// pack 8 fp32 -> hi or lo fp16 int4
__device__ __forceinline__ int4 pack8(const float* v, int p){
  union { int4 i4; __half h[8]; } u;
  #pragma unroll
  for (int e=0;e<8;e++){
    __half hh = __float2half(v[e]);
    u.h[e] = p ? __float2half(v[e] - __half2float(hh)) : hh;
  }
  return u.i4;
}

// ---------------- k_A: attGEMM(t) | decGEMM(t-1) | proj(t-2) | conv(t)+align(t-1) ----------------
// blocks: [0,128) att (c=bid&3,jt=bid>>2) | [128,256) dec | [256,300) proj | [300,556) conv
__global__ __launch_bounds__(512) void k_A(Ptrs P, int t){
  __shared__ __align__(16) __half xf[2][10240];   // 40KB union
  float* smf = (float*)xf;
  int bid = blockIdx.x, tid = threadIdx.x;
  int wid = tid>>6, lane = tid&63;
  int par1 = (t-1)&1;

  if (bid < 128){
    if (t >= 400) return;
    // attGEMM(t): x = [pre_t(256) | ctx(t-1)(512) | ah(t-1)(1024)], hi/lo fp16, 2 K-chunks
    int jt = bid>>2, c = bid&3;
    int jt16 = jt*8 + wid;
    f32x4 acc0 = {0.f,0.f,0.f,0.f}, acc1 = {0.f,0.f,0.f,0.f};
    const float* ctxU0 = P.ctxU + par1*32768;
    const float* denP  = P.den + par1*64;
    for (int half=0; half<2; half++){
      int cc = c*2 + half;
      if (half) __syncthreads();
      for (int i = tid; i < 1792; i += 512){
        int p = i & 1, q = i >> 1;
        int b = q / 28, k8 = q - b*28;
        int kg = cc*224 + k8*8;
        int m = b>>4, ln = ((k8&3)<<4)|(b&15), ksl = k8>>2;
        __half* dst = (p ? xf[1] : xf[0]) + (((ksl<<1)|m)<<9) + ln*8;
        if (kg < 256){
          *(int4*)dst = *(const int4*)((p ? P.preL : P.preH) + (size_t)(t*32+b)*256 + kg);
        } else if (kg < 768){
          int e0 = kg - 256;
          float rdn = rcpf(denP[b*2] + denP[b*2+1]);
          const float* u0 = ctxU0 + b*512 + e0;
          float4 a0 = *(const float4*)u0,        a1 = *(const float4*)(u0+4);
          float4 b0 = *(const float4*)(u0+16384), b1 = *(const float4*)(u0+16388);
          float v[8] = {(a0.x+b0.x)*rdn,(a0.y+b0.y)*rdn,(a0.z+b0.z)*rdn,(a0.w+b0.w)*rdn,
                        (a1.x+b1.x)*rdn,(a1.y+b1.y)*rdn,(a1.z+b1.z)*rdn,(a1.w+b1.w)*rdn};
          *(int4*)dst = pack8(v, p);
        } else {
          *(int4*)dst = *(const int4*)((p ? P.ahpL : P.ahpH) + b*1024 + (kg-768));
        }
      }
      __syncthreads();
      for (int ksl=0; ksl<7; ksl++){
        int ks = cc*7 + ksl;
        f16x8 bw = *(const f16x8*)(P.WAm + (size_t)ks*131072 + (size_t)jt16*512 + lane*8);
        f16x8 a0h = *(const f16x8*)(&xf[0][(ksl<<10) + lane*8]);
        f16x8 a1h = *(const f16x8*)(&xf[0][(ksl<<10) + 512 + lane*8]);
        f16x8 a0l = *(const f16x8*)(&xf[1][(ksl<<10) + lane*8]);
        f16x8 a1l = *(const f16x8*)(&xf[1][(ksl<<10) + 512 + lane*8]);
        acc0 = MFMA161632(a0h, bw, acc0);
        acc1 = MFMA161632(a1h, bw, acc1);
        acc0 = MFMA161632(a0l, bw, acc0);
        acc1 = MFMA161632(a1l, bw, acc1);
      }
    }
    int colj = (jt16<<4) + (lane&15);
    int rb = (lane>>4)<<2;
    float* gA = P.gpA + (size_t)c*131072 + colj;
    #pragma unroll
    for (int r=0;r<4;r++){
      gA[(size_t)(rb + r)*4096]      = acc0[r];
      gA[(size_t)(16 + rb + r)*4096] = acc1[r];
    }
  } else if (bid < 256){
    if (t < 1 || t > 400) return;
    // decGEMM(t-1): x = [ah(t-1)(1024) | ctx(t-1)(512) | dh(t-2)(1024)], 2 K-chunks
    int did = bid - 128;
    int jt = did>>2, c = did&3;
    int jt16 = jt*8 + wid;
    f32x4 acc0 = {0.f,0.f,0.f,0.f}, acc1 = {0.f,0.f,0.f,0.f};
    const float* ctxU0 = P.ctxU + par1*32768;
    const float* denP  = P.den + par1*64;
    for (int half=0; half<2; half++){
      int cc = c*2 + half;
      if (half) __syncthreads();
      for (int i = tid; i < 2560; i += 512){
        int p = i & 1, q = i >> 1;
        int b = q / 40, k8 = q - b*40;
        int kg = cc*320 + k8*8;
        int m = b>>4, ln = ((k8&3)<<4)|(b&15), ksl = k8>>2;
        __half* dst = (p ? xf[1] : xf[0]) + (((ksl<<1)|m)<<9) + ln*8;
        if (kg < 1024){
          *(int4*)dst = *(const int4*)((p ? P.ahpL : P.ahpH) + b*1024 + kg);
        } else if (kg < 1536){
          int e0 = kg - 1024;
          float rdn = rcpf(denP[b*2] + denP[b*2+1]);
          const float* u0 = ctxU0 + b*512 + e0;
          float4 a0 = *(const float4*)u0,        a1 = *(const float4*)(u0+4);
          float4 b0 = *(const float4*)(u0+16384), b1 = *(const float4*)(u0+16388);
          float v[8] = {(a0.x+b0.x)*rdn,(a0.y+b0.y)*rdn,(a0.z+b0.z)*rdn,(a0.w+b0.w)*rdn,
                        (a1.x+b1.x)*rdn,(a1.y+b1.y)*rdn,(a1.z+b1.z)*rdn,(a1.w+b1.w)*rdn};
          *(int4*)dst = pack8(v, p);
        } else {
          *(int4*)dst = *(const int4*)((p ? P.dhL : P.dhH) + b*1024 + (kg-1536));
        }
      }
      __syncthreads();
      for (int ksl=0; ksl<10; ksl++){
        int ks = cc*10 + ksl;
        f16x8 bw = *(const f16x8*)(P.WDm + (size_t)ks*131072 + (size_t)jt16*512 + lane*8);
        f16x8 a0h = *(const f16x8*)(&xf[0][(ksl<<10) + lane*8]);
        f16x8 a1h = *(const f16x8*)(&xf[0][(ksl<<10) + 512 + lane*8]);
        f16x8 a0l = *(const f16x8*)(&xf[1][(ksl<<10) + lane*8]);
        f16x8 a1l = *(const f16x8*)(&xf[1][(ksl<<10) + 512 + lane*8]);
        acc0 = MFMA161632(a0h, bw, acc0);
        acc1 = MFMA161632(a1h, bw, acc1);
        acc0 = MFMA161632(a0l, bw, acc0);
        acc1 = MFMA161632(a1l, bw, acc1);
      }
    }
    int colj = (jt16<<4) + (lane&15);
    int rb = (lane>>4)<<2;
    float* gD = P.gpD + (size_t)c*131072 + colj;
    #pragma unroll
    for (int r=0;r<4;r++){
      gD[(size_t)(rb + r)*4096]      = acc0[r];
      gD[(size_t)(16 + rb + r)*4096] = acc1[r];
    }
  } else if (bid < 300){
    if (t < 2) return;
    // proj(t-2): x = [dh(t-2)(1024) | ctx(t-2)(512)]
    int par2 = t&1;   // == (t-2)&1
    int eb = bid - 256;              // 0..43
    int b0 = (eb&3)*8;
    int row = (eb>>2)*8 + wid;       // 0..87
    bool act = (row <= 80);
    const float* wrow = (row<80) ? (P.Wproj + (size_t)row*1536) : P.Wgate;
    float acc[8];
    #pragma unroll
    for (int bi=0;bi<8;bi++) acc[bi]=0.f;
    for (int i4=tid; i4<2048; i4+=512){
      int bi=i4>>8, kk=(i4&255)<<2;
      *(float4*)(smf + bi*1024 + kk) = *(const float4*)(P.dh + (b0+bi)*1024 + kk);
    }
    __syncthreads();
    if (act){
      #pragma unroll
      for (int kq=0;kq<4;kq++){
        int k0=kq*256+lane*4;
        float4 w4 = *(const float4*)(wrow + k0);
        #pragma unroll
        for (int bi=0;bi<8;bi++){
          float4 x = *(float4*)(smf + bi*1024 + k0);
          acc[bi] += x.x*w4.x + x.y*w4.y + x.z*w4.z + x.w*w4.w;
        }
      }
    }
    __syncthreads();
    for (int i4=tid; i4<1024; i4+=512){
      int bi=i4>>7, kk=(i4&127)<<2;
      int b = b0+bi;
      float rd = rcpf(P.den[par2*64 + b*2] + P.den[par2*64 + b*2 + 1]);
      const float* u0 = P.ctxU + par2*32768 + b*512 + kk;
      float4 a0 = *(const float4*)u0;
      float4 b4 = *(const float4*)(u0+16384);
      *(float4*)(smf + bi*512 + kk) = make_float4((a0.x+b4.x)*rd,(a0.y+b4.y)*rd,
                                                  (a0.z+b4.z)*rd,(a0.w+b4.w)*rd);
    }
    __syncthreads();
    if (act){
      #pragma unroll
      for (int kq=0;kq<2;kq++){
        int k0=kq*256+lane*4;
        float4 w4 = *(const float4*)(wrow + 1024 + k0);
        #pragma unroll
        for (int bi=0;bi<8;bi++){
          float4 x = *(float4*)(smf + bi*512 + k0);
          acc[bi] += x.x*w4.x + x.y*w4.y + x.z*w4.z + x.w*w4.w;
        }
      }
      #pragma unroll
      for (int bi=0;bi<8;bi++){
        float v = acc[bi];
        #pragma unroll
        for (int d=1; d<64; d<<=1) v += __shfl_xor(v, d, 64);
        acc[bi]=v;
      }
      if (lane==0){
        float bias = (row<80)? P.bproj[row] : P.bgate[0];
        #pragma unroll
        for (int bi=0;bi<8;bi++){
          float v = acc[bi]+bias;
          if (row<80) P.out[(size_t)(b0+bi)*32000 + row*400 + (t-2)] = v;
          else        P.out[GATE_OFF + (b0+bi)*400 + (t-2)] = v;
        }
      }
    }
  } else {
    if (t > 400) return;
    // conv(t) using aw(t-1)=exU(t-1)/den, awc(t-1)=awcB[(t-2)&1]+aw(t-1); align(t-1) write
    int gw = (bid-300)*8 + wid;
    int b = gw>>6, rr = gw&63, t0 = (rr>>1)*16, ahalf = rr&1, a = ahalf*64 + lane;
    float d0 = P.den[par1*64 + b*2], d1 = P.den[par1*64 + b*2 + 1];
    float dsum = d0 + d1;
    float rdn = rcpf(dsum);
    const float* exP = P.exU + par1*16384 + b*512;
    const float* awcPrev = P.awcB + (t&1)*16384 + b*512;   // awc(t-2)
    if (t < 400){
      float acc[16];
      #pragma unroll
      for (int tl=0;tl<16;tl++) acc[tl]=0.f;
      #pragma unroll
      for (int c=0;c<2;c++){
        float awin[46];
        #pragma unroll
        for (int i=0;i<46;i++){
          int tt = t0-15+i;
          float v = 0.f;
          if (tt>=0 && tt<512){
            v = exP[tt]*rdn;
            if (c) v += awcPrev[tt];
          }
          awin[i] = v;
        }
        #pragma unroll
        for (int k=0;k<31;k++){
          float mcv = P.Mc[(c*31+k)*128 + a];
          #pragma unroll
          for (int tl=0;tl<16;tl++) acc[tl] += awin[tl + k]*mcv;
        }
      }
      #pragma unroll
      for (int tl=0;tl<16;tl++){
        size_t idx = ((size_t)b*512 + t0+tl)*128 + a;
        P.locH[idx] = __float2half(acc[tl] + (float)P.pmH[idx]);
      }
    }
    if (ahalf==0 && lane<16){
      int s = t0 + lane;
      float ex = exP[s];
      if (t >= 1)
        P.out[ALIGN_OFF + (size_t)b*204800 + (size_t)(t-1)*512 + s] = ex / dsum;
      if (t < 400)
        P.awcB[par1*16384 + b*512 + s] = awcPrev[s] + ex*rdn;   // awc(t-1)
    }
  }
}

// ---------------- k_BC: att-act + q + scores(s-half) + partials | dec-act(t-1) ----------------
// blocks: [0,64) att (b=bid>>1, sh=bid&1) | [64,96) dact
__global__ __launch_bounds__(512) void k_BC(Ptrs P, int t){
  __shared__ float sm[6144];
  int bid = blockIdx.x, tid = threadIdx.x;
  int wid = tid>>6, lane = tid&63;
  if (bid < 64){
    if (t >= 400) return;
    int b = bid>>1, sh = bid&1;
    int par = t&1;
    #pragma unroll
    for (int i=0;i<2;i++){
      int jj = tid + i*512;
      float gi=0.f, gf=0.f, gg=0.f, go=0.f;
      #pragma unroll
      for (int c=0;c<4;c++){
        const float* g = P.gpA + (size_t)(c*32+b)*4096;
        gi += g[jj]; gf += g[1024+jj]; gg += g[2048+jj]; go += g[3072+jj];
      }
      gi += P.bihA[jj]      + P.bhhA[jj];
      gf += P.bihA[1024+jj] + P.bhhA[1024+jj];
      gg += P.bihA[2048+jj] + P.bhhA[2048+jj];
      go += P.bihA[3072+jj] + P.bhhA[3072+jj];
      float c2 = sigf(gf)*P.acp[b*1024+jj] + sigf(gi)*tanhfast(gg);
      float hh = sigf(go)*tanhfast(c2);
      if (sh==0){
        P.acn[b*1024+jj] = c2;
        __half hhh = __float2half(hh);
        P.ahnH[b*1024+jj] = hhh;
        P.ahnL[b*1024+jj] = __float2half(hh - __half2float(hhh));
      }
      sm[jj] = hh;
    }
    __syncthreads();
    // q = ah @ Wq^T (a-major fp16 Wq)
    {
      int a = tid&127, kq = tid>>7;
      const __half* wr = P.WqTh + a*1024 + kq*256;
      const float* xr = sm + kq*256;
      float p = 0.f;
      for (int k2=0; k2<256; k2+=8){
        f16x8 wv = *(const f16x8*)(wr + k2);
        float4 x0 = *(const float4*)(xr + k2);
        float4 x1 = *(const float4*)(xr + k2 + 4);
        p += x0.x*(float)wv[0] + x0.y*(float)wv[1] + x0.z*(float)wv[2] + x0.w*(float)wv[3]
           + x1.x*(float)wv[4] + x1.y*(float)wv[5] + x1.z*(float)wv[6] + x1.w*(float)wv[7];
      }
      sm[1024 + kq*128 + a] = p;
    }
    __syncthreads();
    if (tid < 128) sm[1536+tid] = sm[1024+tid] + sm[1152+tid] + sm[1280+tid] + sm[1408+tid];
    __syncthreads();
    // scores for this s-half (256 s), unnormalized softmax partials
    if (tid < 256){
      int s = sh*256 + tid;
      const __half* lrow = P.locH + ((size_t)b*512 + s)*128;
      float sc = 0.f;
      #pragma unroll
      for (int a=0; a<128; a+=4){
        __half2 h0 = *(const __half2*)(lrow + a);
        __half2 h1 = *(const __half2*)(lrow + a + 2);
        float2 l0 = __half22float2(h0);
        float2 l1 = __half22float2(h1);
        float4 wv = *(const float4*)(P.Wsc + a);
        sc += wv.x*tanhfast(sm[1536+a+0]+l0.x) + wv.y*tanhfast(sm[1536+a+1]+l0.y)
            + wv.z*tanhfast(sm[1536+a+2]+l1.x) + wv.w*tanhfast(sm[1536+a+3]+l1.y);
      }
      float ex = __expf(sc + P.bsc[0]);   // tanh-bounded: safe without max-sub
      sm[1664+tid] = ex;
      P.exU[par*16384 + b*512 + s] = ex;
      float exs = ex;
      #pragma unroll
      for (int d=1; d<64; d<<=1) exs += __shfl_xor(exs, d, 64);
      if (lane==0) sm[1920+wid] = exs;
    }
    __syncthreads();
    if (tid==0)
      P.den[par*64 + b*2 + sh] = sm[1920]+sm[1921]+sm[1922]+sm[1923];
    // ctx partial: ctxU[sh] = sum over this half's s of ex_s * memH[s][e]
    float a8[8];
    #pragma unroll
    for (int e=0;e<8;e++) a8[e]=0.f;
    const __half* mb = P.memH + (size_t)b*262144 + (size_t)(sh*256)*512 + lane*8;
    for (int sl = wid*32; sl < wid*32+32; sl++){
      float wv = sm[1664+sl];
      f16x8 mv = *(const f16x8*)(mb + (size_t)sl*512);
      #pragma unroll
      for (int e=0;e<8;e++) a8[e] += wv*(float)mv[e];
    }
    *(float4*)(&sm[2048 + wid*512 + lane*8])     = make_float4(a8[0],a8[1],a8[2],a8[3]);
    *(float4*)(&sm[2048 + wid*512 + lane*8 + 4]) = make_float4(a8[4],a8[5],a8[6],a8[7]);
    __syncthreads();
    float cv = 0.f;
    #pragma unroll
    for (int u8=0;u8<8;u8++) cv += sm[2048 + u8*512 + tid];
    P.ctxU[par*32768 + sh*16384 + b*512 + tid] = cv;
  } else {
    if (t < 1) return;
    // dec activation for step t-1
    int b = bid - 64;
    #pragma unroll
    for (int i=0;i<2;i++){
      int jj = tid + i*512;
      float gi=0.f, gf=0.f, gg=0.f, go=0.f;
      #pragma unroll
      for (int c=0;c<4;c++){
        const float* g = P.gpD + (size_t)(c*32+b)*4096;
        gi += g[jj]; gf += g[1024+jj]; gg += g[2048+jj]; go += g[3072+jj];
      }
      gi += P.bihD[jj]      + P.bhhD[jj];
      gf += P.bihD[1024+jj] + P.bhhD[1024+jj];
      gg += P.bihD[2048+jj] + P.bhhD[2048+jj];
      go += P.bihD[3072+jj] + P.bhhD[3072+jj];
      float c2 = sigf(gf)*P.dc[b*1024+jj] + sigf(gi)*tanhfast(gg);
      float hh = sigf(go)*tanhfast(c2);
      P.dc[b*1024+jj] = c2;
      P.dh[b*1024+jj] = hh;
      __half hhh = __float2half(hh);
      P.dhH[b*1024+jj] = hhh;
      P.dhL[b*1024+jj] = __float2half(hh - __half2float(hhh));
    }
  }
}

// ---------------- host ----------------
extern "C" void kernel_launch(void* const* d_in, const int* in_sizes, int n_in,
                              void* d_out, int out_size, void* d_ws, size_t ws_size,
                              hipStream_t stream) {
  Ptrs P;
  P.mem   = (const float*)d_in[0];  P.dec   = (const float*)d_in[1];
  P.Wpre1 = (const float*)d_in[2];  P.Wpre2 = (const float*)d_in[3];
  P.WihA  = (const float*)d_in[4];  P.WhhA  = (const float*)d_in[5];
  P.bihA  = (const float*)d_in[6];  P.bhhA  = (const float*)d_in[7];
  P.WihD  = (const float*)d_in[8];  P.WhhD  = (const float*)d_in[9];
  P.bihD  = (const float*)d_in[10]; P.bhhD  = (const float*)d_in[11];
  P.Wq    = (const float*)d_in[12]; P.Wm    = (const float*)d_in[13];
  P.Wsc   = (const float*)d_in[14]; P.bsc   = (const float*)d_in[15];
  P.Wlc   = (const float*)d_in[16]; P.Wld   = (const float*)d_in[17];
  P.Wproj = (const float*)d_in[18]; P.bproj = (const float*)d_in[19];
  P.Wgate = (const float*)d_in[20]; P.bgate = (const float*)d_in[21];
  P.out = (float*)d_out;

  float* ws = (float*)d_ws;
  size_t o = 0;
  P.pmH  = (__half*)(ws + o); o += 1048576;   // [32][512][128] fp16
  P.preH = (__half*)(ws + o); o += 1638400;   // [12800][256] fp16 hi
  P.preL = (__half*)(ws + o); o += 1638400;   // fp16 lo
  P.locH = (__half*)(ws + o); o += 1048576;   // fp16
  P.WqTh = (__half*)(ws + o); o += 65536;     // fp16 [128][1024] a-major
  P.Mc   = ws + o; o += 8192;
  P.W1T  = ws + o; o += 20480;
  P.W2T  = ws + o; o += 65536;
  P.WmT  = ws + o; o += 65536;
  P.gpA  = ws + o; o += 524288;               // [4][32][4096] fp32
  P.gpD  = ws + o; o += 524288;
  float* stateBase = ws + o;
  float* AC[2]; AC[0] = ws + o; o += 32768; AC[1] = ws + o; o += 32768;
  P.dh  = ws + o; o += 32768;
  P.dc  = ws + o; o += 32768;
  __half* AHH[2]; AHH[0]=(__half*)(ws+o); o+=16384; AHH[1]=(__half*)(ws+o); o+=16384;
  __half* AHL[2]; AHL[0]=(__half*)(ws+o); o+=16384; AHL[1]=(__half*)(ws+o); o+=16384;
  P.dhH = (__half*)(ws+o); o += 16384;
  P.dhL = (__half*)(ws+o); o += 16384;
  P.awcB = ws + o; o += 32768;                // [2][32][512]
  P.exU  = ws + o; o += 32768;                // [2][32][512]
  P.ctxU = ws + o; o += 65536;                // [2][2][32][512]
  P.den  = ws + o; o += 256;                  // [2][32][2]
  int stateN = (int)((ws + o) - stateBase);
  P.memH = (__half*)(ws + o); o += 4194304;   // [32][512][512] fp16
  P.WAm  = (__half*)(ws + o); o += 3670016;   // [56][256][64][8] fp16 frag
  P.WDm  = (__half*)(ws + o); o += 5242880;   // [80][256][64][8] fp16 frag
  P.p1   = (float*)P.WAm;                     // prologue scratch aliases WAm region

  hipLaunchKernelGGL(k_init, dim3((stateN+255)/256), dim3(256), 0, stream, stateBase, stateN);
  hipLaunchKernelGGL(k_memh, dim3(8192), dim3(1024), 0, stream, P);
  hipLaunchKernelGGL(k_xform, dim3(1136), dim3(256), 0, stream, P);
  hipLaunchKernelGGL(k_pn1, dim3(1600), dim3(256), 0, stream, P);
  hipLaunchKernelGGL(k_pn2, dim3(1600), dim3(256), 0, stream, P);
  hipLaunchKernelGGL(k_pm,  dim3(2048), dim3(256), 0, stream, P);
  hipLaunchKernelGGL(k_tA,  dim3(3584), dim3(256), 0, stream, P);
  hipLaunchKernelGGL(k_tD,  dim3(5120), dim3(256), 0, stream, P);

  for (int t=0; t<=401; t++){
    Ptrs Q = P;
    Q.acp  = AC[t&1];    Q.acn  = AC[(t+1)&1];
    Q.ahpH = AHH[t&1];   Q.ahnH = AHH[(t+1)&1];
    Q.ahpL = AHL[t&1];   Q.ahnL = AHL[(t+1)&1];
    hipLaunchKernelGGL(k_A, dim3(556), dim3(512), 0, stream, Q, t);
    if (t <= 400)
      hipLaunchKernelGGL(k_BC, dim3(96), dim3(512), 0, stream, Q, t);
  }
}